// Round 1
// baseline (1370.560 us; speedup 1.0000x reference)
//
#include <hip/hip_runtime.h>

#define NB 4
#define NS 2048
#define ND 2048
#define NH 16
#define NHD 128

typedef __bf16 bf16;
typedef __attribute__((ext_vector_type(8))) __bf16 bf16x8;
typedef __attribute__((ext_vector_type(4))) __bf16 bf16x4;
typedef __attribute__((ext_vector_type(4))) float f32x4;

#define MFMA(a, b, c) __builtin_amdgcn_mfma_f32_16x16x32_bf16(a, b, c, 0, 0, 0)

// ---------------------------------------------------------------------------
// Kernel 1: fused QKV projection + bias + per-head RMSNorm, bf16 out (B,H,S,Hd)
// C[M=8192][N=2048] = X[M][K] @ W[N][K]^T ; tile 128x128, BK=64, 4 waves 2x2.
// N-tile (128) == head_dim so the RMSNorm reduction is block-local.
// ---------------------------------------------------------------------------
__global__ __launch_bounds__(256) void qkv_gemm(
    const float* __restrict__ Xq, const float* __restrict__ Xk, const float* __restrict__ Xv,
    const float* __restrict__ Wq, const float* __restrict__ Wk, const float* __restrict__ Wv,
    const float* __restrict__ bq, const float* __restrict__ bk, const float* __restrict__ bv,
    const float* __restrict__ qw, const float* __restrict__ kw,
    bf16* __restrict__ Oq, bf16* __restrict__ Ok, bf16* __restrict__ Ov)
{
    const int mat = blockIdx.z;
    const float* X    = (mat == 0) ? Xq : (mat == 1) ? Xk : Xv;
    const float* W    = (mat == 0) ? Wq : (mat == 1) ? Wk : Wv;
    const float* bias = (mat == 0) ? bq : (mat == 1) ? bk : bv;
    const float* nw   = (mat == 0) ? qw : kw;
    bf16* Out         = (mat == 0) ? Oq : (mat == 1) ? Ok : Ov;

    // stride 88 bf16 = 176 B (16B-aligned for ds_read_b128, 2-way-max bank alias)
    __shared__ bf16 As[128][88];
    __shared__ bf16 Bs[128][88];
    __shared__ float red[128][2];
    __shared__ float scl[128];

    const int tid  = threadIdx.x;
    const int lane = tid & 63;
    const int w    = tid >> 6;
    const int wm   = w & 1, wn = w >> 1;
    const int quad = lane >> 4, l15 = lane & 15;
    const int m0   = blockIdx.y * 128;
    const int n0   = blockIdx.x * 128;   // head index == blockIdx.x

    f32x4 acc[4][4] = {};

    const int sr = tid >> 4;          // 0..15
    const int sc = (tid & 15) * 4;    // 0..60

    for (int k0 = 0; k0 < ND; k0 += 64) {
        #pragma unroll
        for (int i = 0; i < 8; ++i) {
            int r = sr + i * 16;
            float4 a4 = *reinterpret_cast<const float4*>(X + (size_t)(m0 + r) * ND + k0 + sc);
            float4 b4 = *reinterpret_cast<const float4*>(W + (size_t)(n0 + r) * ND + k0 + sc);
            bf16x4 at, bt;
            at[0] = (bf16)a4.x; at[1] = (bf16)a4.y; at[2] = (bf16)a4.z; at[3] = (bf16)a4.w;
            bt[0] = (bf16)b4.x; bt[1] = (bf16)b4.y; bt[2] = (bf16)b4.z; bt[3] = (bf16)b4.w;
            *reinterpret_cast<bf16x4*>(&As[r][sc]) = at;
            *reinterpret_cast<bf16x4*>(&Bs[r][sc]) = bt;
        }
        __syncthreads();
        #pragma unroll
        for (int ks = 0; ks < 2; ++ks) {
            const int kb = ks * 32 + quad * 8;
            bf16x8 af[4], bfr[4];
            #pragma unroll
            for (int mi = 0; mi < 4; ++mi)
                af[mi] = *reinterpret_cast<const bf16x8*>(&As[wm * 64 + mi * 16 + l15][kb]);
            #pragma unroll
            for (int ni = 0; ni < 4; ++ni)
                bfr[ni] = *reinterpret_cast<const bf16x8*>(&Bs[wn * 64 + ni * 16 + l15][kb]);
            #pragma unroll
            for (int mi = 0; mi < 4; ++mi)
                #pragma unroll
                for (int ni = 0; ni < 4; ++ni)
                    acc[mi][ni] = MFMA(af[mi], bfr[ni], acc[mi][ni]);
        }
        __syncthreads();
    }

    // epilogue: bias
    #pragma unroll
    for (int ni = 0; ni < 4; ++ni) {
        float bn = bias[n0 + wn * 64 + ni * 16 + l15];
        #pragma unroll
        for (int mi = 0; mi < 4; ++mi)
            #pragma unroll
            for (int r = 0; r < 4; ++r)
                acc[mi][ni][r] += bn;
    }

    // per-head RMSNorm (Q and K only): sum of squares over the 128 cols
    if (mat < 2) {
        #pragma unroll
        for (int mi = 0; mi < 4; ++mi) {
            float ss[4];
            #pragma unroll
            for (int r = 0; r < 4; ++r) {
                float s = 0.f;
                #pragma unroll
                for (int ni = 0; ni < 4; ++ni) { float v = acc[mi][ni][r]; s += v * v; }
                ss[r] = s;
            }
            #pragma unroll
            for (int off = 1; off < 16; off <<= 1)
                #pragma unroll
                for (int r = 0; r < 4; ++r)
                    ss[r] += __shfl_xor(ss[r], off);
            if (l15 == 0) {
                #pragma unroll
                for (int r = 0; r < 4; ++r)
                    red[wm * 64 + mi * 16 + quad * 4 + r][wn] = ss[r];
            }
        }
        __syncthreads();
        if (tid < 128)
            scl[tid] = rsqrtf((red[tid][0] + red[tid][1]) * (1.0f / 128.0f) + 1e-6f);
        __syncthreads();
    }

    const int hh = blockIdx.x;
    #pragma unroll
    for (int mi = 0; mi < 4; ++mi) {
        #pragma unroll
        for (int r = 0; r < 4; ++r) {
            int row = wm * 64 + mi * 16 + quad * 4 + r;
            int mg  = m0 + row;
            int bb  = mg >> 11;            // token -> batch (S = 2048)
            int ssi = mg & (NS - 1);
            size_t base = (((size_t)bb * NH + hh) * NS + ssi) * NHD;
            float sc_r = (mat < 2) ? scl[row] : 1.0f;
            #pragma unroll
            for (int ni = 0; ni < 4; ++ni) {
                int col = wn * 64 + ni * 16 + l15;   // == d within head
                float v = acc[mi][ni][r] * sc_r;
                if (mat < 2) v *= nw[col];
                Out[base + col] = (bf16)v;
            }
        }
    }
}

// ---------------------------------------------------------------------------
// Kernel 2: flash attention. One block per (b, h, 64-row q tile). 4 waves,
// each wave owns 16 q rows. K/V tiles of 64 rows. Online softmax in-register
// (row state in (quad,reg); shuffle-xor reductions over lane&15).
// ---------------------------------------------------------------------------
__global__ __launch_bounds__(256) void flash_attn(
    const bf16* __restrict__ Q, const bf16* __restrict__ K, const bf16* __restrict__ V,
    bf16* __restrict__ O)
{
    __shared__ bf16 Qs[64][136];   // stride 272 B
    __shared__ bf16 Ks[64][136];
    __shared__ bf16 Vs[64][136];
    __shared__ bf16 Ps[64][72];    // stride 144 B (16B-aligned)

    const int tid  = threadIdx.x;
    const int lane = tid & 63;
    const int w    = tid >> 6;
    const int quad = lane >> 4, l15 = lane & 15;
    const int b    = blockIdx.z, h = blockIdx.y;
    const int q0   = blockIdx.x * 64;
    const size_t hb = ((size_t)b * NH + h) * (size_t)NS * NHD;
    const bf16* Qh = Q + hb;
    const bf16* Kh = K + hb;
    const bf16* Vh = V + hb;

    // stage Q tile (64 x 128)
    #pragma unroll
    for (int i = 0; i < 4; ++i) {
        int r = (tid >> 4) + i * 16;
        int c = (tid & 15) * 8;
        *reinterpret_cast<bf16x8*>(&Qs[r][c]) =
            *reinterpret_cast<const bf16x8*>(Qh + (size_t)(q0 + r) * NHD + c);
    }

    f32x4 o[8] = {};
    float m_r[4] = {-1e30f, -1e30f, -1e30f, -1e30f};
    float l_r[4] = {0.f, 0.f, 0.f, 0.f};
    const float scale = 0.08838834764831845f;   // 1/sqrt(128)

    for (int kt = 0; kt < NS / 64; ++kt) {
        const int k0 = kt * 64;
        #pragma unroll
        for (int i = 0; i < 4; ++i) {
            int r = (tid >> 4) + i * 16;
            int c = (tid & 15) * 8;
            *reinterpret_cast<bf16x8*>(&Ks[r][c]) =
                *reinterpret_cast<const bf16x8*>(Kh + (size_t)(k0 + r) * NHD + c);
            *reinterpret_cast<bf16x8*>(&Vs[r][c]) =
                *reinterpret_cast<const bf16x8*>(Vh + (size_t)(k0 + r) * NHD + c);
        }
        __syncthreads();

        // S = Q K^T : wave's 16 q rows x 64 k cols
        f32x4 sacc[4] = {};
        #pragma unroll
        for (int ks = 0; ks < 4; ++ks) {
            bf16x8 a = *reinterpret_cast<const bf16x8*>(&Qs[w * 16 + l15][ks * 32 + quad * 8]);
            #pragma unroll
            for (int ni = 0; ni < 4; ++ni) {
                bf16x8 bb = *reinterpret_cast<const bf16x8*>(&Ks[ni * 16 + l15][ks * 32 + quad * 8]);
                sacc[ni] = MFMA(a, bb, sacc[ni]);
            }
        }

        // online softmax, fp32, in-register. Row r_local = quad*4 + reg.
        float mt[4];
        #pragma unroll
        for (int r = 0; r < 4; ++r) {
            #pragma unroll
            for (int ni = 0; ni < 4; ++ni) sacc[ni][r] *= scale;
            float mm = fmaxf(fmaxf(sacc[0][r], sacc[1][r]), fmaxf(sacc[2][r], sacc[3][r]));
            #pragma unroll
            for (int off = 1; off < 16; off <<= 1) mm = fmaxf(mm, __shfl_xor(mm, off));
            mt[r] = mm;
        }
        float al[4];
        #pragma unroll
        for (int r = 0; r < 4; ++r) {
            float mn = fmaxf(m_r[r], mt[r]);
            al[r] = __expf(m_r[r] - mn);
            m_r[r] = mn;
            float s = 0.f;
            #pragma unroll
            for (int ni = 0; ni < 4; ++ni) {
                float p = __expf(sacc[ni][r] - mn);
                sacc[ni][r] = p;
                s += p;
            }
            #pragma unroll
            for (int off = 1; off < 16; off <<= 1) s += __shfl_xor(s, off);
            l_r[r] = l_r[r] * al[r] + s;
        }

        // P -> LDS (A-operand layout round trip), rescale O accumulator
        #pragma unroll
        for (int ni = 0; ni < 4; ++ni)
            #pragma unroll
            for (int r = 0; r < 4; ++r)
                Ps[w * 16 + quad * 4 + r][ni * 16 + l15] = (bf16)sacc[ni][r];
        #pragma unroll
        for (int ci = 0; ci < 8; ++ci)
            #pragma unroll
            for (int r = 0; r < 4; ++r)
                o[ci][r] *= al[r];

        __syncthreads();

        // O += P @ V : contraction over 64 keys (2 MFMA k-steps)
        #pragma unroll
        for (int ks = 0; ks < 2; ++ks) {
            bf16x8 a = *reinterpret_cast<const bf16x8*>(&Ps[w * 16 + l15][ks * 32 + quad * 8]);
            #pragma unroll
            for (int ci = 0; ci < 8; ++ci) {
                bf16x8 bb;
                #pragma unroll
                for (int j = 0; j < 8; ++j)
                    bb[j] = Vs[ks * 32 + quad * 8 + j][ci * 16 + l15];
                o[ci] = MFMA(a, bb, o[ci]);
            }
        }
        __syncthreads();
    }

    // epilogue: O /= l, write (B,S,D) bf16
    #pragma unroll
    for (int r = 0; r < 4; ++r) {
        int sg = q0 + w * 16 + quad * 4 + r;
        float inv = 1.0f / l_r[r];
        size_t base = ((size_t)b * NS + sg) * ND + (size_t)h * NHD;
        #pragma unroll
        for (int ci = 0; ci < 8; ++ci)
            O[base + ci * 16 + l15] = (bf16)(o[ci][r] * inv);
    }
}

// ---------------------------------------------------------------------------
// Kernel 3: output projection. out[M][N] = A[M][K](bf16) @ Wo[N][K]^T + bo, fp32 out
// ---------------------------------------------------------------------------
__global__ __launch_bounds__(256) void oproj_gemm(
    const bf16* __restrict__ A, const float* __restrict__ W,
    const float* __restrict__ bias, float* __restrict__ Out)
{
    __shared__ bf16 As[128][88];
    __shared__ bf16 Bs[128][88];

    const int tid  = threadIdx.x;
    const int lane = tid & 63;
    const int w    = tid >> 6;
    const int wm   = w & 1, wn = w >> 1;
    const int quad = lane >> 4, l15 = lane & 15;
    const int m0   = blockIdx.y * 128;
    const int n0   = blockIdx.x * 128;

    f32x4 acc[4][4] = {};

    for (int k0 = 0; k0 < ND; k0 += 64) {
        #pragma unroll
        for (int i = 0; i < 4; ++i) {   // A: bf16, 8 elems/load
            int r = (tid >> 3) + i * 32;
            int c = (tid & 7) * 8;
            *reinterpret_cast<bf16x8*>(&As[r][c]) =
                *reinterpret_cast<const bf16x8*>(A + (size_t)(m0 + r) * ND + k0 + c);
        }
        #pragma unroll
        for (int i = 0; i < 8; ++i) {   // B: fp32 -> bf16
            int r = (tid >> 4) + i * 16;
            int c = (tid & 15) * 4;
            float4 b4 = *reinterpret_cast<const float4*>(W + (size_t)(n0 + r) * ND + k0 + c);
            bf16x4 bt;
            bt[0] = (bf16)b4.x; bt[1] = (bf16)b4.y; bt[2] = (bf16)b4.z; bt[3] = (bf16)b4.w;
            *reinterpret_cast<bf16x4*>(&Bs[r][c]) = bt;
        }
        __syncthreads();
        #pragma unroll
        for (int ks = 0; ks < 2; ++ks) {
            const int kb = ks * 32 + quad * 8;
            bf16x8 af[4], bfr[4];
            #pragma unroll
            for (int mi = 0; mi < 4; ++mi)
                af[mi] = *reinterpret_cast<const bf16x8*>(&As[wm * 64 + mi * 16 + l15][kb]);
            #pragma unroll
            for (int ni = 0; ni < 4; ++ni)
                bfr[ni] = *reinterpret_cast<const bf16x8*>(&Bs[wn * 64 + ni * 16 + l15][kb]);
            #pragma unroll
            for (int mi = 0; mi < 4; ++mi)
                #pragma unroll
                for (int ni = 0; ni < 4; ++ni)
                    acc[mi][ni] = MFMA(af[mi], bfr[ni], acc[mi][ni]);
        }
        __syncthreads();
    }

    #pragma unroll
    for (int ni = 0; ni < 4; ++ni) {
        int col = n0 + wn * 64 + ni * 16 + l15;
        float bn = bias[col];
        #pragma unroll
        for (int mi = 0; mi < 4; ++mi)
            #pragma unroll
            for (int r = 0; r < 4; ++r) {
                int mg = m0 + wm * 64 + mi * 16 + quad * 4 + r;
                Out[(size_t)mg * ND + col] = acc[mi][ni][r] + bn;
            }
    }
}

// ---------------------------------------------------------------------------
extern "C" void kernel_launch(void* const* d_in, const int* in_sizes, int n_in,
                              void* d_out, int out_size, void* d_ws, size_t ws_size,
                              hipStream_t stream)
{
    const float* q  = (const float*)d_in[0];
    const float* k  = (const float*)d_in[1];
    const float* v  = (const float*)d_in[2];
    const float* Wq = (const float*)d_in[3];
    const float* bq = (const float*)d_in[4];
    const float* Wk = (const float*)d_in[5];
    const float* bk = (const float*)d_in[6];
    const float* Wv = (const float*)d_in[7];
    const float* bv = (const float*)d_in[8];
    const float* Wo = (const float*)d_in[9];
    const float* bo = (const float*)d_in[10];
    const float* qw = (const float*)d_in[11];
    const float* kw = (const float*)d_in[12];
    float* out = (float*)d_out;

    const size_t nE = (size_t)NB * NH * NS * NHD;   // 16,777,216 elems
    bf16* Qn = (bf16*)d_ws;          // (B,H,S,Hd) normalized Q
    bf16* Kn = Qn + nE;              // (B,H,S,Hd) normalized K
    bf16* Vp = Kn + nE;              // (B,H,S,Hd) V
    bf16* Ob = Vp + nE;              // (B,S,D) attention output
    // total ws use: 4 * 32 MiB = 128 MiB

    qkv_gemm<<<dim3(16, 64, 3), dim3(256), 0, stream>>>(
        q, k, v, Wq, Wk, Wv, bq, bk, bv, qw, kw, Qn, Kn, Vp);
    flash_attn<<<dim3(32, 16, 4), dim3(256), 0, stream>>>(Qn, Kn, Vp, Ob);
    oproj_gemm<<<dim3(16, 64), dim3(256), 0, stream>>>(Ob, Wo, bo, out);
}

// Round 2
// 1121.043 us; speedup vs baseline: 1.2226x; 1.2226x over previous
//
#include <hip/hip_runtime.h>

#define NB 4
#define NS 2048
#define ND 2048
#define NH 16
#define NHD 128

typedef __bf16 bf16;
typedef __attribute__((ext_vector_type(8))) __bf16 bf16x8;
typedef __attribute__((ext_vector_type(4))) __bf16 bf16x4;
typedef __attribute__((ext_vector_type(4))) float f32x4;

#define MFMA(a, b, c) __builtin_amdgcn_mfma_f32_16x16x32_bf16(a, b, c, 0, 0, 0)

// ---------------------------------------------------------------------------
// Kernel 1: fused QKV projection + bias + per-head RMSNorm (Q,K) bf16 out
// (B,H,S,Hd); V is written TRANSPOSED as (B,H,Hd,S) for the flash PV step.
// C[M=8192][N=2048] = X[M][K] @ W[N][K]^T ; tile 128x128, BK=64, 4 waves 2x2.
// ---------------------------------------------------------------------------
__global__ __launch_bounds__(256) void qkv_gemm(
    const float* __restrict__ Xq, const float* __restrict__ Xk, const float* __restrict__ Xv,
    const float* __restrict__ Wq, const float* __restrict__ Wk, const float* __restrict__ Wv,
    const float* __restrict__ bq, const float* __restrict__ bk, const float* __restrict__ bv,
    const float* __restrict__ qw, const float* __restrict__ kw,
    bf16* __restrict__ Oq, bf16* __restrict__ Ok, bf16* __restrict__ Ov)
{
    const int mat = blockIdx.z;
    const float* X    = (mat == 0) ? Xq : (mat == 1) ? Xk : Xv;
    const float* W    = (mat == 0) ? Wq : (mat == 1) ? Wk : Wv;
    const float* bias = (mat == 0) ? bq : (mat == 1) ? bk : bv;
    const float* nw   = (mat == 0) ? qw : kw;
    bf16* Out         = (mat == 0) ? Oq : (mat == 1) ? Ok : Ov;

    // pool: As[128][88] | Bs[128][88] during k-loop; aliased by Ts[128][136]
    // (transpose staging, mat==2 only) after the final barrier.
    __shared__ alignas(16) char pool[45056];
    __shared__ float red[128][2];
    __shared__ float scl[128];
    bf16 (*As)[88] = (bf16(*)[88])pool;
    bf16 (*Bs)[88] = (bf16(*)[88])(pool + 22528);

    const int tid  = threadIdx.x;
    const int lane = tid & 63;
    const int w    = tid >> 6;
    const int wm   = w & 1, wn = w >> 1;
    const int quad = lane >> 4, l15 = lane & 15;
    const int m0   = blockIdx.y * 128;
    const int n0   = blockIdx.x * 128;   // head index == blockIdx.x

    f32x4 acc[4][4] = {};

    const int sr = tid >> 4;          // 0..15
    const int sc = (tid & 15) * 4;    // 0..60

    for (int k0 = 0; k0 < ND; k0 += 64) {
        #pragma unroll
        for (int i = 0; i < 8; ++i) {
            int r = sr + i * 16;
            float4 a4 = *reinterpret_cast<const float4*>(X + (size_t)(m0 + r) * ND + k0 + sc);
            float4 b4 = *reinterpret_cast<const float4*>(W + (size_t)(n0 + r) * ND + k0 + sc);
            bf16x4 at, bt;
            at[0] = (bf16)a4.x; at[1] = (bf16)a4.y; at[2] = (bf16)a4.z; at[3] = (bf16)a4.w;
            bt[0] = (bf16)b4.x; bt[1] = (bf16)b4.y; bt[2] = (bf16)b4.z; bt[3] = (bf16)b4.w;
            *reinterpret_cast<bf16x4*>(&As[r][sc]) = at;
            *reinterpret_cast<bf16x4*>(&Bs[r][sc]) = bt;
        }
        __syncthreads();
        #pragma unroll
        for (int ks = 0; ks < 2; ++ks) {
            const int kb = ks * 32 + quad * 8;
            bf16x8 af[4], bfr[4];
            #pragma unroll
            for (int mi = 0; mi < 4; ++mi)
                af[mi] = *reinterpret_cast<const bf16x8*>(&As[wm * 64 + mi * 16 + l15][kb]);
            #pragma unroll
            for (int ni = 0; ni < 4; ++ni)
                bfr[ni] = *reinterpret_cast<const bf16x8*>(&Bs[wn * 64 + ni * 16 + l15][kb]);
            #pragma unroll
            for (int mi = 0; mi < 4; ++mi)
                #pragma unroll
                for (int ni = 0; ni < 4; ++ni)
                    acc[mi][ni] = MFMA(af[mi], bfr[ni], acc[mi][ni]);
        }
        __syncthreads();
    }

    // epilogue: bias
    #pragma unroll
    for (int ni = 0; ni < 4; ++ni) {
        float bn = bias[n0 + wn * 64 + ni * 16 + l15];
        #pragma unroll
        for (int mi = 0; mi < 4; ++mi)
            #pragma unroll
            for (int r = 0; r < 4; ++r)
                acc[mi][ni][r] += bn;
    }

    const int hh = blockIdx.x;

    if (mat == 2) {
        // ---- V path: transpose tile in LDS, write (B,H,Hd,S) coalesced ----
        // (k-loop's final __syncthreads guarantees As/Bs reads are done)
        bf16 (*Ts)[136] = (bf16(*)[136])pool;
        #pragma unroll
        for (int mi = 0; mi < 4; ++mi)
            #pragma unroll
            for (int ni = 0; ni < 4; ++ni) {
                bf16x4 t;
                #pragma unroll
                for (int r = 0; r < 4; ++r) t[r] = (bf16)acc[mi][ni][r];
                *reinterpret_cast<bf16x4*>(
                    &Ts[wn * 64 + ni * 16 + l15][wm * 64 + mi * 16 + quad * 4]) = t;
            }
        __syncthreads();
        const int bb = m0 >> 11;               // 128-row tile is within one batch
        const int s0 = m0 & (NS - 1);
        const size_t obase = ((size_t)bb * NH + hh) * (size_t)NHD * NS;
        #pragma unroll
        for (int i = 0; i < 8; ++i) {
            int d = i * 16 + (tid >> 4);
            int c = (tid & 15) * 8;
            *reinterpret_cast<bf16x8*>(Out + obase + (size_t)d * NS + s0 + c) =
                *reinterpret_cast<const bf16x8*>(&Ts[d][c]);
        }
        return;
    }

    // ---- Q/K path: per-head RMSNorm over the 128 cols, write (B,H,S,Hd) ----
    #pragma unroll
    for (int mi = 0; mi < 4; ++mi) {
        float ss[4];
        #pragma unroll
        for (int r = 0; r < 4; ++r) {
            float s = 0.f;
            #pragma unroll
            for (int ni = 0; ni < 4; ++ni) { float v = acc[mi][ni][r]; s += v * v; }
            ss[r] = s;
        }
        #pragma unroll
        for (int off = 1; off < 16; off <<= 1)
            #pragma unroll
            for (int r = 0; r < 4; ++r)
                ss[r] += __shfl_xor(ss[r], off);
        if (l15 == 0) {
            #pragma unroll
            for (int r = 0; r < 4; ++r)
                red[wm * 64 + mi * 16 + quad * 4 + r][wn] = ss[r];
        }
    }
    __syncthreads();
    if (tid < 128)
        scl[tid] = rsqrtf((red[tid][0] + red[tid][1]) * (1.0f / 128.0f) + 1e-6f);
    __syncthreads();

    #pragma unroll
    for (int mi = 0; mi < 4; ++mi) {
        #pragma unroll
        for (int r = 0; r < 4; ++r) {
            int row = wm * 64 + mi * 16 + quad * 4 + r;
            int mg  = m0 + row;
            int bb  = mg >> 11;            // token -> batch (S = 2048)
            int ssi = mg & (NS - 1);
            size_t base = (((size_t)bb * NH + hh) * NS + ssi) * NHD;
            float sc_r = scl[row];
            #pragma unroll
            for (int ni = 0; ni < 4; ++ni) {
                int col = wn * 64 + ni * 16 + l15;   // == d within head
                float v = acc[mi][ni][r] * sc_r * nw[col];
                Out[base + col] = (bf16)v;
            }
        }
    }
}

// ---------------------------------------------------------------------------
// Kernel 2: flash attention. One block per (b, h, 64-row q tile). 4 waves,
// each wave owns 16 q rows. K tiles of 64 keys; V comes in TRANSPOSED
// (b,h,d,s) so PV B-fragments are contiguous ds_read_b128. Q fragments live
// in registers. Ps aliases the Ks region (wave-private rows; barrier between
// last K read and first P write). Online softmax in-register.
// ---------------------------------------------------------------------------
__global__ __launch_bounds__(256, 4) void flash_attn(
    const bf16* __restrict__ Q, const bf16* __restrict__ K, const bf16* __restrict__ Vt,
    bf16* __restrict__ O)
{
    __shared__ alignas(16) char pool[17408];      // Ks[64][136] | Ps[64][72]
    __shared__ bf16 VtS[128][72];                 // d-major V tile
    bf16 (*Ks)[136] = (bf16(*)[136])pool;
    bf16 (*Ps)[72]  = (bf16(*)[72])pool;

    const int tid  = threadIdx.x;
    const int lane = tid & 63;
    const int w    = tid >> 6;
    const int quad = lane >> 4, l15 = lane & 15;
    const int b    = blockIdx.z, h = blockIdx.y;
    const int q0   = blockIdx.x * 64;
    const size_t hb = ((size_t)b * NH + h) * (size_t)NS * NHD;
    const bf16* Qh  = Q + hb;
    const bf16* Kh  = K + hb;
    const bf16* Vth = Vt + hb;    // (b,h,d,s)

    // Q fragments in registers: A[m=q][k=d], m = w*16 + l15, k = ks*32+quad*8+j
    bf16x8 qf[4];
    #pragma unroll
    for (int ks = 0; ks < 4; ++ks)
        qf[ks] = *reinterpret_cast<const bf16x8*>(
            Qh + (size_t)(q0 + w * 16 + l15) * NHD + ks * 32 + quad * 8);

    f32x4 o[8] = {};
    float m_r[4] = {-1e30f, -1e30f, -1e30f, -1e30f};
    float l_r[4] = {0.f, 0.f, 0.f, 0.f};
    const float scale = 0.08838834764831845f;   // 1/sqrt(128)

    for (int kt = 0; kt < NS / 64; ++kt) {
        const int k0 = kt * 64;
        // stage K tile (64 keys x 128 d)
        #pragma unroll
        for (int i = 0; i < 4; ++i) {
            int r = (tid >> 4) + i * 16;
            int c = (tid & 15) * 8;
            *reinterpret_cast<bf16x8*>(&Ks[r][c]) =
                *reinterpret_cast<const bf16x8*>(Kh + (size_t)(k0 + r) * NHD + c);
        }
        // stage Vt tile (128 d x 64 keys)
        #pragma unroll
        for (int i = 0; i < 4; ++i) {
            int r = (tid >> 3) + i * 32;
            int c = (tid & 7) * 8;
            *reinterpret_cast<bf16x8*>(&VtS[r][c]) =
                *reinterpret_cast<const bf16x8*>(Vth + (size_t)r * NS + k0 + c);
        }
        __syncthreads();

        // S = Q K^T : wave's 16 q rows x 64 k cols
        f32x4 sacc[4] = {};
        #pragma unroll
        for (int ks = 0; ks < 4; ++ks) {
            #pragma unroll
            for (int ni = 0; ni < 4; ++ni) {
                bf16x8 bb = *reinterpret_cast<const bf16x8*>(&Ks[ni * 16 + l15][ks * 32 + quad * 8]);
                sacc[ni] = MFMA(qf[ks], bb, sacc[ni]);
            }
        }

        // online softmax, fp32, in-register. Row r_local = quad*4 + reg.
        float mt[4];
        #pragma unroll
        for (int r = 0; r < 4; ++r) {
            #pragma unroll
            for (int ni = 0; ni < 4; ++ni) sacc[ni][r] *= scale;
            float mm = fmaxf(fmaxf(sacc[0][r], sacc[1][r]), fmaxf(sacc[2][r], sacc[3][r]));
            #pragma unroll
            for (int off = 1; off < 16; off <<= 1) mm = fmaxf(mm, __shfl_xor(mm, off));
            mt[r] = mm;
        }
        float al[4];
        #pragma unroll
        for (int r = 0; r < 4; ++r) {
            float mn = fmaxf(m_r[r], mt[r]);
            al[r] = __expf(m_r[r] - mn);
            m_r[r] = mn;
            float s = 0.f;
            #pragma unroll
            for (int ni = 0; ni < 4; ++ni) {
                float p = __expf(sacc[ni][r] - mn);
                sacc[ni][r] = p;
                s += p;
            }
            #pragma unroll
            for (int off = 1; off < 16; off <<= 1) s += __shfl_xor(s, off);
            l_r[r] = l_r[r] * al[r] + s;
        }

        __syncthreads();   // all Ks reads complete before Ps overwrites the region

        // P -> LDS (C-layout -> A-operand layout), rescale O accumulator
        #pragma unroll
        for (int ni = 0; ni < 4; ++ni)
            #pragma unroll
            for (int r = 0; r < 4; ++r)
                Ps[w * 16 + quad * 4 + r][ni * 16 + l15] = (bf16)sacc[ni][r];
        #pragma unroll
        for (int ci = 0; ci < 8; ++ci)
            #pragma unroll
            for (int r = 0; r < 4; ++r)
                o[ci][r] *= al[r];

        // O += P @ V : Ps rows are wave-private, lgkmcnt handles write->read
        #pragma unroll
        for (int ks = 0; ks < 2; ++ks) {
            bf16x8 a = *reinterpret_cast<const bf16x8*>(&Ps[w * 16 + l15][ks * 32 + quad * 8]);
            #pragma unroll
            for (int ci = 0; ci < 8; ++ci) {
                bf16x8 bb = *reinterpret_cast<const bf16x8*>(&VtS[ci * 16 + l15][ks * 32 + quad * 8]);
                o[ci] = MFMA(a, bb, o[ci]);
            }
        }
        __syncthreads();
    }

    // epilogue: O /= l, write (B,S,D) bf16
    #pragma unroll
    for (int r = 0; r < 4; ++r) {
        int sg = q0 + w * 16 + quad * 4 + r;
        float inv = 1.0f / l_r[r];
        size_t base = ((size_t)b * NS + sg) * ND + (size_t)h * NHD;
        #pragma unroll
        for (int ci = 0; ci < 8; ++ci)
            O[base + ci * 16 + l15] = (bf16)(o[ci][r] * inv);
    }
}

// ---------------------------------------------------------------------------
// Kernel 3: output projection. out[M][N] = A[M][K](bf16) @ Wo[N][K]^T + bo, fp32 out
// ---------------------------------------------------------------------------
__global__ __launch_bounds__(256) void oproj_gemm(
    const bf16* __restrict__ A, const float* __restrict__ W,
    const float* __restrict__ bias, float* __restrict__ Out)
{
    __shared__ bf16 As[128][88];
    __shared__ bf16 Bs[128][88];

    const int tid  = threadIdx.x;
    const int lane = tid & 63;
    const int w    = tid >> 6;
    const int wm   = w & 1, wn = w >> 1;
    const int quad = lane >> 4, l15 = lane & 15;
    const int m0   = blockIdx.y * 128;
    const int n0   = blockIdx.x * 128;

    f32x4 acc[4][4] = {};

    for (int k0 = 0; k0 < ND; k0 += 64) {
        #pragma unroll
        for (int i = 0; i < 4; ++i) {   // A: bf16, 8 elems/load
            int r = (tid >> 3) + i * 32;
            int c = (tid & 7) * 8;
            *reinterpret_cast<bf16x8*>(&As[r][c]) =
                *reinterpret_cast<const bf16x8*>(A + (size_t)(m0 + r) * ND + k0 + c);
        }
        #pragma unroll
        for (int i = 0; i < 8; ++i) {   // B: fp32 -> bf16
            int r = (tid >> 4) + i * 16;
            int c = (tid & 15) * 4;
            float4 b4 = *reinterpret_cast<const float4*>(W + (size_t)(n0 + r) * ND + k0 + c);
            bf16x4 bt;
            bt[0] = (bf16)b4.x; bt[1] = (bf16)b4.y; bt[2] = (bf16)b4.z; bt[3] = (bf16)b4.w;
            *reinterpret_cast<bf16x4*>(&Bs[r][c]) = bt;
        }
        __syncthreads();
        #pragma unroll
        for (int ks = 0; ks < 2; ++ks) {
            const int kb = ks * 32 + quad * 8;
            bf16x8 af[4], bfr[4];
            #pragma unroll
            for (int mi = 0; mi < 4; ++mi)
                af[mi] = *reinterpret_cast<const bf16x8*>(&As[wm * 64 + mi * 16 + l15][kb]);
            #pragma unroll
            for (int ni = 0; ni < 4; ++ni)
                bfr[ni] = *reinterpret_cast<const bf16x8*>(&Bs[wn * 64 + ni * 16 + l15][kb]);
            #pragma unroll
            for (int mi = 0; mi < 4; ++mi)
                #pragma unroll
                for (int ni = 0; ni < 4; ++ni)
                    acc[mi][ni] = MFMA(af[mi], bfr[ni], acc[mi][ni]);
        }
        __syncthreads();
    }

    #pragma unroll
    for (int ni = 0; ni < 4; ++ni) {
        int col = n0 + wn * 64 + ni * 16 + l15;
        float bn = bias[col];
        #pragma unroll
        for (int mi = 0; mi < 4; ++mi)
            #pragma unroll
            for (int r = 0; r < 4; ++r) {
                int mg = m0 + wm * 64 + mi * 16 + quad * 4 + r;
                Out[(size_t)mg * ND + col] = acc[mi][ni][r] + bn;
            }
    }
}

// ---------------------------------------------------------------------------
extern "C" void kernel_launch(void* const* d_in, const int* in_sizes, int n_in,
                              void* d_out, int out_size, void* d_ws, size_t ws_size,
                              hipStream_t stream)
{
    const float* q  = (const float*)d_in[0];
    const float* k  = (const float*)d_in[1];
    const float* v  = (const float*)d_in[2];
    const float* Wq = (const float*)d_in[3];
    const float* bq = (const float*)d_in[4];
    const float* Wk = (const float*)d_in[5];
    const float* bk = (const float*)d_in[6];
    const float* Wv = (const float*)d_in[7];
    const float* bv = (const float*)d_in[8];
    const float* Wo = (const float*)d_in[9];
    const float* bo = (const float*)d_in[10];
    const float* qw = (const float*)d_in[11];
    const float* kw = (const float*)d_in[12];
    float* out = (float*)d_out;

    const size_t nE = (size_t)NB * NH * NS * NHD;   // 16,777,216 elems
    bf16* Qn = (bf16*)d_ws;          // (B,H,S,Hd) normalized Q
    bf16* Kn = Qn + nE;              // (B,H,S,Hd) normalized K
    bf16* Vtp = Kn + nE;             // (B,H,Hd,S) V transposed
    bf16* Ob = Vtp + nE;             // (B,S,D) attention output
    // total ws use: 4 * 32 MiB = 128 MiB

    qkv_gemm<<<dim3(16, 64, 3), dim3(256), 0, stream>>>(
        q, k, v, Wq, Wk, Wv, bq, bk, bv, qw, kw, Qn, Kn, Vtp);
    flash_attn<<<dim3(32, 16, 4), dim3(256), 0, stream>>>(Qn, Kn, Vtp, Ob);
    oproj_gemm<<<dim3(16, 64), dim3(256), 0, stream>>>(Ob, Wo, bo, out);
}

// Round 3
// 1032.120 us; speedup vs baseline: 1.3279x; 1.0862x over previous
//
#include <hip/hip_runtime.h>

#define NB 4
#define NS 2048
#define ND 2048
#define NH 16
#define NHD 128

typedef __bf16 bf16;
typedef __attribute__((ext_vector_type(8))) __bf16 bf16x8;
typedef __attribute__((ext_vector_type(4))) __bf16 bf16x4;
typedef __attribute__((ext_vector_type(4))) float f32x4;

#define MFMA(a, b, c) __builtin_amdgcn_mfma_f32_16x16x32_bf16(a, b, c, 0, 0, 0)

// async global->LDS, 16 B per lane. LDS dest = wave-uniform base + lane*16.
__device__ __forceinline__ void gload16(const bf16* g, bf16* l) {
    __builtin_amdgcn_global_load_lds(
        (const __attribute__((address_space(1))) void*)g,
        (__attribute__((address_space(3))) void*)l, 16, 0, 0);
}

// ---------------------------------------------------------------------------
// Kernel 0: fp32 -> bf16 convert, 8 elems/thread, exact grid (n % 2048 == 0)
// ---------------------------------------------------------------------------
__global__ __launch_bounds__(256) void cvt_bf16(const float* __restrict__ src,
                                                bf16* __restrict__ dst)
{
    size_t i = ((size_t)blockIdx.x * 256 + threadIdx.x) * 8;
    float4 a = *reinterpret_cast<const float4*>(src + i);
    float4 b = *reinterpret_cast<const float4*>(src + i + 4);
    bf16x8 o;
    o[0] = (bf16)a.x; o[1] = (bf16)a.y; o[2] = (bf16)a.z; o[3] = (bf16)a.w;
    o[4] = (bf16)b.x; o[5] = (bf16)b.y; o[6] = (bf16)b.z; o[7] = (bf16)b.w;
    *reinterpret_cast<bf16x8*>(dst + i) = o;
}

// ---------------------------------------------------------------------------
// Kernel 1: fused QKV projection + bias + per-head RMSNorm (Q,K) bf16 out
// (B,H,S,Hd); V written TRANSPOSED (B,H,Hd,S). bf16 inputs, m97-style
// global_load_lds staging (unpadded LDS, 16B/lane), 128x128 tile, BK=64.
// ---------------------------------------------------------------------------
__global__ __launch_bounds__(256) void qkv_gemm(
    const bf16* __restrict__ Xb, const bf16* __restrict__ Wb,
    const float* __restrict__ bq, const float* __restrict__ bk, const float* __restrict__ bv,
    const float* __restrict__ qw, const float* __restrict__ kw,
    bf16* __restrict__ Oq, bf16* __restrict__ Ok, bf16* __restrict__ Ov)
{
    const int mat = blockIdx.z;
    const bf16* X     = Xb + (size_t)mat * (size_t)NB * NS * ND;
    const bf16* W     = Wb + (size_t)mat * ND * ND;
    const float* bias = (mat == 0) ? bq : (mat == 1) ? bk : bv;
    const float* nw   = (mat == 0) ? qw : kw;
    bf16* Out         = (mat == 0) ? Oq : (mat == 1) ? Ok : Ov;

    // pool: As[128*64] | Bs[128*64] bf16 during k-loop (32 KB, unpadded for
    // global_load_lds); aliased by Ts[128][136] (34816 B) in the V epilogue.
    __shared__ alignas(16) char pool[34816];
    __shared__ float red[128][2];
    __shared__ float scl[128];
    bf16* As = (bf16*)pool;
    bf16* Bs = (bf16*)(pool + 16384);

    const int tid  = threadIdx.x;
    const int lane = tid & 63;
    const int w    = tid >> 6;
    const int wm   = w & 1, wn = w >> 1;
    const int quad = lane >> 4, l15 = lane & 15;
    const int m0   = blockIdx.y * 128;
    const int n0   = blockIdx.x * 128;   // head index == blockIdx.x

    const int rsub = lane >> 3;          // 0..7
    const int csub = (lane & 7) * 8;     // 0..56

    f32x4 acc[4][4] = {};

    for (int k0 = 0; k0 < ND; k0 += 64) {
        const bf16* Ag = X + (size_t)m0 * ND + k0;
        const bf16* Bg = W + (size_t)n0 * ND + k0;
        #pragma unroll
        for (int i = 0; i < 4; ++i) {
            int idx = w * 4 + i;         // 16 chunks of 8 rows x 64 cols
            gload16(Ag + (size_t)(idx * 8 + rsub) * ND + csub, As + idx * 512);
            gload16(Bg + (size_t)(idx * 8 + rsub) * ND + csub, Bs + idx * 512);
        }
        __syncthreads();
        #pragma unroll
        for (int ks = 0; ks < 2; ++ks) {
            const int kb = ks * 32 + quad * 8;
            bf16x8 af[4], bfr[4];
            #pragma unroll
            for (int mi = 0; mi < 4; ++mi)
                af[mi] = *reinterpret_cast<const bf16x8*>(As + (wm * 64 + mi * 16 + l15) * 64 + kb);
            #pragma unroll
            for (int ni = 0; ni < 4; ++ni)
                bfr[ni] = *reinterpret_cast<const bf16x8*>(Bs + (wn * 64 + ni * 16 + l15) * 64 + kb);
            #pragma unroll
            for (int mi = 0; mi < 4; ++mi)
                #pragma unroll
                for (int ni = 0; ni < 4; ++ni)
                    acc[mi][ni] = MFMA(af[mi], bfr[ni], acc[mi][ni]);
        }
        __syncthreads();
    }

    // epilogue: bias
    #pragma unroll
    for (int ni = 0; ni < 4; ++ni) {
        float bn = bias[n0 + wn * 64 + ni * 16 + l15];
        #pragma unroll
        for (int mi = 0; mi < 4; ++mi)
            #pragma unroll
            for (int r = 0; r < 4; ++r)
                acc[mi][ni][r] += bn;
    }

    const int hh = blockIdx.x;

    if (mat == 2) {
        // ---- V path: transpose tile in LDS, write (B,H,Hd,S) coalesced ----
        bf16 (*Ts)[136] = (bf16(*)[136])pool;
        #pragma unroll
        for (int mi = 0; mi < 4; ++mi)
            #pragma unroll
            for (int ni = 0; ni < 4; ++ni) {
                bf16x4 t;
                #pragma unroll
                for (int r = 0; r < 4; ++r) t[r] = (bf16)acc[mi][ni][r];
                *reinterpret_cast<bf16x4*>(
                    &Ts[wn * 64 + ni * 16 + l15][wm * 64 + mi * 16 + quad * 4]) = t;
            }
        __syncthreads();
        const int bb = m0 >> 11;               // 128-row tile is within one batch
        const int s0 = m0 & (NS - 1);
        const size_t obase = ((size_t)bb * NH + hh) * (size_t)NHD * NS;
        #pragma unroll
        for (int i = 0; i < 8; ++i) {
            int d = i * 16 + (tid >> 4);
            int c = (tid & 15) * 8;
            *reinterpret_cast<bf16x8*>(Out + obase + (size_t)d * NS + s0 + c) =
                *reinterpret_cast<const bf16x8*>(&Ts[d][c]);
        }
        return;
    }

    // ---- Q/K path: per-head RMSNorm over the 128 cols, write (B,H,S,Hd) ----
    #pragma unroll
    for (int mi = 0; mi < 4; ++mi) {
        float ss[4];
        #pragma unroll
        for (int r = 0; r < 4; ++r) {
            float s = 0.f;
            #pragma unroll
            for (int ni = 0; ni < 4; ++ni) { float v = acc[mi][ni][r]; s += v * v; }
            ss[r] = s;
        }
        #pragma unroll
        for (int off = 1; off < 16; off <<= 1)
            #pragma unroll
            for (int r = 0; r < 4; ++r)
                ss[r] += __shfl_xor(ss[r], off);
        if (l15 == 0) {
            #pragma unroll
            for (int r = 0; r < 4; ++r)
                red[wm * 64 + mi * 16 + quad * 4 + r][wn] = ss[r];
        }
    }
    __syncthreads();
    if (tid < 128)
        scl[tid] = rsqrtf((red[tid][0] + red[tid][1]) * (1.0f / 128.0f) + 1e-6f);
    __syncthreads();

    #pragma unroll
    for (int mi = 0; mi < 4; ++mi) {
        #pragma unroll
        for (int r = 0; r < 4; ++r) {
            int row = wm * 64 + mi * 16 + quad * 4 + r;
            int mg  = m0 + row;
            int bb  = mg >> 11;            // token -> batch (S = 2048)
            int ssi = mg & (NS - 1);
            size_t base = (((size_t)bb * NH + hh) * NS + ssi) * NHD;
            float sc_r = scl[row];
            #pragma unroll
            for (int ni = 0; ni < 4; ++ni) {
                int col = wn * 64 + ni * 16 + l15;   // == d within head
                float v = acc[mi][ni][r] * sc_r * nw[col];
                Out[base + col] = (bf16)v;
            }
        }
    }
}

// ---------------------------------------------------------------------------
// Kernel 2: flash attention. One block per (b, h, 64-row q tile). 4 waves,
// each wave owns 16 q rows. K tiles of 64 keys; V comes in TRANSPOSED
// (b,h,d,s) so PV B-fragments are contiguous ds_read_b128. Q fragments live
// in registers. Ps aliases the Ks region. Online softmax in-register.
// ---------------------------------------------------------------------------
__global__ __launch_bounds__(256, 4) void flash_attn(
    const bf16* __restrict__ Q, const bf16* __restrict__ K, const bf16* __restrict__ Vt,
    bf16* __restrict__ O)
{
    __shared__ alignas(16) char pool[17408];      // Ks[64][136] | Ps[64][72]
    __shared__ bf16 VtS[128][72];                 // d-major V tile
    bf16 (*Ks)[136] = (bf16(*)[136])pool;
    bf16 (*Ps)[72]  = (bf16(*)[72])pool;

    const int tid  = threadIdx.x;
    const int lane = tid & 63;
    const int w    = tid >> 6;
    const int quad = lane >> 4, l15 = lane & 15;
    const int b    = blockIdx.z, h = blockIdx.y;
    const int q0   = blockIdx.x * 64;
    const size_t hb = ((size_t)b * NH + h) * (size_t)NS * NHD;
    const bf16* Qh  = Q + hb;
    const bf16* Kh  = K + hb;
    const bf16* Vth = Vt + hb;    // (b,h,d,s)

    // Q fragments in registers: A[m=q][k=d], m = w*16 + l15, k = ks*32+quad*8+j
    bf16x8 qf[4];
    #pragma unroll
    for (int ks = 0; ks < 4; ++ks)
        qf[ks] = *reinterpret_cast<const bf16x8*>(
            Qh + (size_t)(q0 + w * 16 + l15) * NHD + ks * 32 + quad * 8);

    f32x4 o[8] = {};
    float m_r[4] = {-1e30f, -1e30f, -1e30f, -1e30f};
    float l_r[4] = {0.f, 0.f, 0.f, 0.f};
    const float scale = 0.08838834764831845f;   // 1/sqrt(128)

    for (int kt = 0; kt < NS / 64; ++kt) {
        const int k0 = kt * 64;
        // stage K tile (64 keys x 128 d)
        #pragma unroll
        for (int i = 0; i < 4; ++i) {
            int r = (tid >> 4) + i * 16;
            int c = (tid & 15) * 8;
            *reinterpret_cast<bf16x8*>(&Ks[r][c]) =
                *reinterpret_cast<const bf16x8*>(Kh + (size_t)(k0 + r) * NHD + c);
        }
        // stage Vt tile (128 d x 64 keys)
        #pragma unroll
        for (int i = 0; i < 4; ++i) {
            int r = (tid >> 3) + i * 32;
            int c = (tid & 7) * 8;
            *reinterpret_cast<bf16x8*>(&VtS[r][c]) =
                *reinterpret_cast<const bf16x8*>(Vth + (size_t)r * NS + k0 + c);
        }
        __syncthreads();

        // S = Q K^T : wave's 16 q rows x 64 k cols
        f32x4 sacc[4] = {};
        #pragma unroll
        for (int ks = 0; ks < 4; ++ks) {
            #pragma unroll
            for (int ni = 0; ni < 4; ++ni) {
                bf16x8 bb = *reinterpret_cast<const bf16x8*>(&Ks[ni * 16 + l15][ks * 32 + quad * 8]);
                sacc[ni] = MFMA(qf[ks], bb, sacc[ni]);
            }
        }

        // online softmax, fp32, in-register. Row r_local = quad*4 + reg.
        float mt[4];
        #pragma unroll
        for (int r = 0; r < 4; ++r) {
            #pragma unroll
            for (int ni = 0; ni < 4; ++ni) sacc[ni][r] *= scale;
            float mm = fmaxf(fmaxf(sacc[0][r], sacc[1][r]), fmaxf(sacc[2][r], sacc[3][r]));
            #pragma unroll
            for (int off = 1; off < 16; off <<= 1) mm = fmaxf(mm, __shfl_xor(mm, off));
            mt[r] = mm;
        }
        float al[4];
        #pragma unroll
        for (int r = 0; r < 4; ++r) {
            float mn = fmaxf(m_r[r], mt[r]);
            al[r] = __expf(m_r[r] - mn);
            m_r[r] = mn;
            float s = 0.f;
            #pragma unroll
            for (int ni = 0; ni < 4; ++ni) {
                float p = __expf(sacc[ni][r] - mn);
                sacc[ni][r] = p;
                s += p;
            }
            #pragma unroll
            for (int off = 1; off < 16; off <<= 1) s += __shfl_xor(s, off);
            l_r[r] = l_r[r] * al[r] + s;
        }

        __syncthreads();   // all Ks reads complete before Ps overwrites the region

        // P -> LDS (C-layout -> A-operand layout), rescale O accumulator
        #pragma unroll
        for (int ni = 0; ni < 4; ++ni)
            #pragma unroll
            for (int r = 0; r < 4; ++r)
                Ps[w * 16 + quad * 4 + r][ni * 16 + l15] = (bf16)sacc[ni][r];
        #pragma unroll
        for (int ci = 0; ci < 8; ++ci)
            #pragma unroll
            for (int r = 0; r < 4; ++r)
                o[ci][r] *= al[r];

        // O += P @ V : Ps rows are wave-private, lgkmcnt handles write->read
        #pragma unroll
        for (int ks = 0; ks < 2; ++ks) {
            bf16x8 a = *reinterpret_cast<const bf16x8*>(&Ps[w * 16 + l15][ks * 32 + quad * 8]);
            #pragma unroll
            for (int ci = 0; ci < 8; ++ci) {
                bf16x8 bb = *reinterpret_cast<const bf16x8*>(&VtS[ci * 16 + l15][ks * 32 + quad * 8]);
                o[ci] = MFMA(a, bb, o[ci]);
            }
        }
        __syncthreads();
    }

    // epilogue: O /= l, write (B,S,D) bf16
    #pragma unroll
    for (int r = 0; r < 4; ++r) {
        int sg = q0 + w * 16 + quad * 4 + r;
        float inv = 1.0f / l_r[r];
        size_t base = ((size_t)b * NS + sg) * ND + (size_t)h * NHD;
        #pragma unroll
        for (int ci = 0; ci < 8; ++ci)
            O[base + ci * 16 + l15] = (bf16)(o[ci][r] * inv);
    }
}

// ---------------------------------------------------------------------------
// Kernel 3: output projection. out[M][N] = A[M][K](bf16) @ Wo[N][K]^T + bo,
// fp32 out. Same m97-style staging as qkv_gemm.
// ---------------------------------------------------------------------------
__global__ __launch_bounds__(256) void oproj_gemm(
    const bf16* __restrict__ A, const bf16* __restrict__ W,
    const float* __restrict__ bias, float* __restrict__ Out)
{
    __shared__ alignas(16) bf16 As[128 * 64];
    __shared__ alignas(16) bf16 Bs[128 * 64];

    const int tid  = threadIdx.x;
    const int lane = tid & 63;
    const int w    = tid >> 6;
    const int wm   = w & 1, wn = w >> 1;
    const int quad = lane >> 4, l15 = lane & 15;
    const int m0   = blockIdx.y * 128;
    const int n0   = blockIdx.x * 128;

    const int rsub = lane >> 3;
    const int csub = (lane & 7) * 8;

    f32x4 acc[4][4] = {};

    for (int k0 = 0; k0 < ND; k0 += 64) {
        const bf16* Ag = A + (size_t)m0 * ND + k0;
        const bf16* Bg = W + (size_t)n0 * ND + k0;
        #pragma unroll
        for (int i = 0; i < 4; ++i) {
            int idx = w * 4 + i;
            gload16(Ag + (size_t)(idx * 8 + rsub) * ND + csub, As + idx * 512);
            gload16(Bg + (size_t)(idx * 8 + rsub) * ND + csub, Bs + idx * 512);
        }
        __syncthreads();
        #pragma unroll
        for (int ks = 0; ks < 2; ++ks) {
            const int kb = ks * 32 + quad * 8;
            bf16x8 af[4], bfr[4];
            #pragma unroll
            for (int mi = 0; mi < 4; ++mi)
                af[mi] = *reinterpret_cast<const bf16x8*>(As + (wm * 64 + mi * 16 + l15) * 64 + kb);
            #pragma unroll
            for (int ni = 0; ni < 4; ++ni)
                bfr[ni] = *reinterpret_cast<const bf16x8*>(Bs + (wn * 64 + ni * 16 + l15) * 64 + kb);
            #pragma unroll
            for (int mi = 0; mi < 4; ++mi)
                #pragma unroll
                for (int ni = 0; ni < 4; ++ni)
                    acc[mi][ni] = MFMA(af[mi], bfr[ni], acc[mi][ni]);
        }
        __syncthreads();
    }

    #pragma unroll
    for (int ni = 0; ni < 4; ++ni) {
        int col = n0 + wn * 64 + ni * 16 + l15;
        float bn = bias[col];
        #pragma unroll
        for (int mi = 0; mi < 4; ++mi)
            #pragma unroll
            for (int r = 0; r < 4; ++r) {
                int mg = m0 + wm * 64 + mi * 16 + quad * 4 + r;
                Out[(size_t)mg * ND + col] = acc[mi][ni][r] + bn;
            }
    }
}

// ---------------------------------------------------------------------------
extern "C" void kernel_launch(void* const* d_in, const int* in_sizes, int n_in,
                              void* d_out, int out_size, void* d_ws, size_t ws_size,
                              hipStream_t stream)
{
    const float* q  = (const float*)d_in[0];
    const float* k  = (const float*)d_in[1];
    const float* v  = (const float*)d_in[2];
    const float* Wq = (const float*)d_in[3];
    const float* bq = (const float*)d_in[4];
    const float* Wk = (const float*)d_in[5];
    const float* bk = (const float*)d_in[6];
    const float* Wv = (const float*)d_in[7];
    const float* bv = (const float*)d_in[8];
    const float* Wo = (const float*)d_in[9];
    const float* bo = (const float*)d_in[10];
    const float* qw = (const float*)d_in[11];
    const float* kw = (const float*)d_in[12];
    float* out = (float*)d_out;

    const size_t nX = (size_t)NB * NS * ND;   // 16,777,216
    const size_t nW = (size_t)ND * ND;        //  4,194,304

    // ws layout (bf16): Xb[3*nX] | Wb[4*nW] | Qn[nX] | Kn[nX] | Vtp[nX]
    // Ob aliases Xb (Xb dead after qkv_gemm; Ob written by flash_attn).
    bf16* Xb  = (bf16*)d_ws;
    bf16* Wb  = Xb + 3 * nX;
    bf16* Qn  = Wb + 4 * nW;
    bf16* Kn  = Qn + nX;
    bf16* Vtp = Kn + nX;
    bf16* Ob  = Xb;
    // total: (6*nX + 4*nW) * 2 B ~= 235 MB

    cvt_bf16<<<8192, 256, 0, stream>>>(q,  Xb);
    cvt_bf16<<<8192, 256, 0, stream>>>(k,  Xb + nX);
    cvt_bf16<<<8192, 256, 0, stream>>>(v,  Xb + 2 * nX);
    cvt_bf16<<<2048, 256, 0, stream>>>(Wq, Wb);
    cvt_bf16<<<2048, 256, 0, stream>>>(Wk, Wb + nW);
    cvt_bf16<<<2048, 256, 0, stream>>>(Wv, Wb + 2 * nW);
    cvt_bf16<<<2048, 256, 0, stream>>>(Wo, Wb + 3 * nW);

    qkv_gemm<<<dim3(16, 64, 3), dim3(256), 0, stream>>>(
        Xb, Wb, bq, bk, bv, qw, kw, Qn, Kn, Vtp);
    flash_attn<<<dim3(32, 16, 4), dim3(256), 0, stream>>>(Qn, Kn, Vtp, Ob);
    oproj_gemm<<<dim3(16, 64), dim3(256), 0, stream>>>(Ob, Wb + 3 * nW, bo, out);
}